// Round 3
// baseline (1435.832 us; speedup 1.0000x reference)
//
#include <hip/hip_runtime.h>
#include <hip/hip_bf16.h>

typedef unsigned short u16;
typedef __attribute__((ext_vector_type(8))) short short8;
typedef __attribute__((ext_vector_type(4))) float floatx4;

#define BATCH 16
#define CDIM 512
#define NSPAT 1024
#define NGROUP 8

__device__ __forceinline__ u16 f2bf(float f) {
    unsigned u = __float_as_uint(f);
    u += 0x7FFFu + ((u >> 16) & 1u);   // RNE
    return (u16)(u >> 16);
}

// ---------------- GroupNorm ----------------
__global__ void gn_stats_kernel(const float* __restrict__ x, float* __restrict__ stats) {
    __shared__ float rs[4], rss[4];
    int bg = blockIdx.x;  // 0..127 (b*8+g); one group = 64 ch * 1024 = 65536 contiguous floats
    const float4* xv = (const float4*)(x + (size_t)bg * 65536);
    float s = 0.f, ss = 0.f;
    for (int i = threadIdx.x; i < 16384; i += 256) {
        float4 v = xv[i];
        s += v.x + v.y + v.z + v.w;
        ss += v.x * v.x + v.y * v.y + v.z * v.z + v.w * v.w;
    }
#pragma unroll
    for (int off = 32; off; off >>= 1) { s += __shfl_down(s, off); ss += __shfl_down(ss, off); }
    int wave = threadIdx.x >> 6, lane = threadIdx.x & 63;
    if (lane == 0) { rs[wave] = s; rss[wave] = ss; }
    __syncthreads();
    if (threadIdx.x == 0) {
        float S1 = rs[0] + rs[1] + rs[2] + rs[3];
        float S2 = rss[0] + rss[1] + rss[2] + rss[3];
        float mean = S1 * (1.f / 65536.f);
        float var = S2 * (1.f / 65536.f) - mean * mean;
        stats[bg * 2] = mean;
        stats[bg * 2 + 1] = rsqrtf(var + 1e-5f);
    }
}

__global__ void gn_apply_kernel(const float* __restrict__ x, const float* __restrict__ gamma,
                                const float* __restrict__ beta, const float* __restrict__ stats,
                                float* __restrict__ h) {
    int vec = blockIdx.x * 256 + threadIdx.x;  // 4 floats per thread
    int e = vec << 2;
    int c = (e >> 10) & 511;
    int bg = e >> 16;
    float mean = stats[bg * 2], rstd = stats[bg * 2 + 1];
    float ga = gamma[c] * rstd;
    float be = beta[c] - mean * ga;
    float4 v = ((const float4*)x)[vec];
    float4 o;
    o.x = v.x * ga + be; o.y = v.y * ga + be; o.z = v.z * ga + be; o.w = v.w * ga + be;
    ((float4*)h)[vec] = o;
}

// ---------------- Softmax (one block per row of 1024 fp32) ----------------
__global__ void softmax_kernel(const float* __restrict__ S, float* __restrict__ P) {
    __shared__ float red[8];
    size_t row = blockIdx.x;
    const float4* sr = (const float4*)(S + (row << 10));
    float4 v = sr[threadIdx.x];
    float mx = fmaxf(fmaxf(v.x, v.y), fmaxf(v.z, v.w));
#pragma unroll
    for (int off = 32; off; off >>= 1) mx = fmaxf(mx, __shfl_down(mx, off));
    int wave = threadIdx.x >> 6, lane = threadIdx.x & 63;
    if (lane == 0) red[wave] = mx;
    __syncthreads();
    mx = fmaxf(fmaxf(red[0], red[1]), fmaxf(red[2], red[3]));
    float e0 = __expf(v.x - mx), e1 = __expf(v.y - mx), e2 = __expf(v.z - mx), e3 = __expf(v.w - mx);
    float s = e0 + e1 + e2 + e3;
#pragma unroll
    for (int off = 32; off; off >>= 1) s += __shfl_down(s, off);
    if (lane == 0) red[4 + wave] = s;
    __syncthreads();
    float inv = 1.f / (red[4] + red[5] + red[6] + red[7]);
    float4 o;
    o.x = e0 * inv; o.y = e1 * inv; o.z = e2 * inv; o.w = e3 * inv;
    ((float4*)P)[(row << 8) + threadIdx.x] = o;
}

// ---------------- Generic GEMM: fp32 global, bf16 MFMA, fp32 accum ----------------
// C[m][n] = sum_k A'[m][k]*B'[k][n];  A' = TA ? A^T (A stored [K,M]) : A [M,K]
//                                     B' = TB ? B^T (B stored [N,K]) : B [K,N]
// EPI: 0 = +bias ; 1 = *scale ; 2 = plain ; 3 = +bias+resid     (all fp32 out)
#define BM 64
#define BN 64
#define BK 32
#define LSTR 40  // padded LDS row stride (shorts); 80 B rows, 16 B-aligned chunks

template <int TA, int TB, int EPI>
__launch_bounds__(256)
__global__ void gemm_mfma(const float* __restrict__ A, const float* __restrict__ B,
                          float* __restrict__ Cout, const float* __restrict__ bias,
                          const float* __restrict__ resid,
                          int M, int N, int K, int lda, int ldb,
                          unsigned long sA, unsigned long sB, unsigned long sC,
                          unsigned long sR, float scale) {
    __shared__ u16 As[BM * LSTR];
    __shared__ u16 Bs[BN * LSTR];
    int tid = threadIdx.x;
    int lane = tid & 63;
    int wave = tid >> 6;
    int quad = lane >> 4;
    int lrow = lane & 15;
    int wm = (wave >> 1) << 5;
    int wn = (wave & 1) << 5;
    int m0 = blockIdx.y * BM;
    int n0 = blockIdx.x * BN;
    const float* Ab = A + sA * blockIdx.z;
    const float* Bb = B + sB * blockIdx.z;

    floatx4 acc[2][2];
#pragma unroll
    for (int i = 0; i < 2; ++i)
#pragma unroll
        for (int j = 0; j < 2; ++j) acc[i][j] = (floatx4){0.f, 0.f, 0.f, 0.f};

    for (int k0 = 0; k0 < K; k0 += BK) {
        if (TA == 0) {
            int r = tid >> 2, c8 = (tid & 3) << 3;
            const float* src = Ab + (size_t)(m0 + r) * lda + k0 + c8;
            float4 v0 = *(const float4*)src, v1 = *(const float4*)(src + 4);
            short8 t;
            t[0] = (short)f2bf(v0.x); t[1] = (short)f2bf(v0.y);
            t[2] = (short)f2bf(v0.z); t[3] = (short)f2bf(v0.w);
            t[4] = (short)f2bf(v1.x); t[5] = (short)f2bf(v1.y);
            t[6] = (short)f2bf(v1.z); t[7] = (short)f2bf(v1.w);
            *(short8*)&As[r * LSTR + c8] = t;
        } else {
            int kk = tid >> 3, m8 = (tid & 7) << 3;
            const float* src = Ab + (size_t)(k0 + kk) * lda + m0 + m8;
            float4 v0 = *(const float4*)src, v1 = *(const float4*)(src + 4);
            As[(m8 + 0) * LSTR + kk] = f2bf(v0.x);
            As[(m8 + 1) * LSTR + kk] = f2bf(v0.y);
            As[(m8 + 2) * LSTR + kk] = f2bf(v0.z);
            As[(m8 + 3) * LSTR + kk] = f2bf(v0.w);
            As[(m8 + 4) * LSTR + kk] = f2bf(v1.x);
            As[(m8 + 5) * LSTR + kk] = f2bf(v1.y);
            As[(m8 + 6) * LSTR + kk] = f2bf(v1.z);
            As[(m8 + 7) * LSTR + kk] = f2bf(v1.w);
        }
        if (TB == 0) {
            int kk = tid >> 3, n8 = (tid & 7) << 3;
            const float* src = Bb + (size_t)(k0 + kk) * ldb + n0 + n8;
            float4 v0 = *(const float4*)src, v1 = *(const float4*)(src + 4);
            Bs[(n8 + 0) * LSTR + kk] = f2bf(v0.x);
            Bs[(n8 + 1) * LSTR + kk] = f2bf(v0.y);
            Bs[(n8 + 2) * LSTR + kk] = f2bf(v0.z);
            Bs[(n8 + 3) * LSTR + kk] = f2bf(v0.w);
            Bs[(n8 + 4) * LSTR + kk] = f2bf(v1.x);
            Bs[(n8 + 5) * LSTR + kk] = f2bf(v1.y);
            Bs[(n8 + 6) * LSTR + kk] = f2bf(v1.z);
            Bs[(n8 + 7) * LSTR + kk] = f2bf(v1.w);
        } else {
            int r = tid >> 2, c8 = (tid & 3) << 3;
            const float* src = Bb + (size_t)(n0 + r) * ldb + k0 + c8;
            float4 v0 = *(const float4*)src, v1 = *(const float4*)(src + 4);
            short8 t;
            t[0] = (short)f2bf(v0.x); t[1] = (short)f2bf(v0.y);
            t[2] = (short)f2bf(v0.z); t[3] = (short)f2bf(v0.w);
            t[4] = (short)f2bf(v1.x); t[5] = (short)f2bf(v1.y);
            t[6] = (short)f2bf(v1.z); t[7] = (short)f2bf(v1.w);
            *(short8*)&Bs[r * LSTR + c8] = t;
        }
        __syncthreads();
        short8 af[2], bfr[2];
#pragma unroll
        for (int t = 0; t < 2; ++t)
            af[t] = *(const short8*)&As[(wm + t * 16 + lrow) * LSTR + (quad << 3)];
#pragma unroll
        for (int t = 0; t < 2; ++t)
            bfr[t] = *(const short8*)&Bs[(wn + t * 16 + lrow) * LSTR + (quad << 3)];
#pragma unroll
        for (int i = 0; i < 2; ++i)
#pragma unroll
            for (int j = 0; j < 2; ++j)
                acc[i][j] = __builtin_amdgcn_mfma_f32_16x16x32_bf16(af[i], bfr[j], acc[i][j], 0, 0, 0);
        __syncthreads();
    }

    float* Cb = Cout + sC * blockIdx.z;
    const float* Rb = resid ? (resid + sR * blockIdx.z) : nullptr;
#pragma unroll
    for (int i = 0; i < 2; ++i)
#pragma unroll
        for (int j = 0; j < 2; ++j)
#pragma unroll
            for (int r = 0; r < 4; ++r) {
                int row = m0 + wm + i * 16 + quad * 4 + r;
                int col = n0 + wn + j * 16 + lrow;
                size_t off = (size_t)row * N + col;
                float v = acc[i][j][r];
                if (EPI == 1) v *= scale;
                if (EPI == 0 || EPI == 3) v += bias[row];
                if (EPI == 3) v += Rb[off];
                Cb[off] = v;
            }
}

// ---------------- launch ----------------
extern "C" void kernel_launch(void* const* d_in, const int* in_sizes, int n_in,
                              void* d_out, int out_size, void* d_ws, size_t ws_size,
                              hipStream_t stream) {
    const float* x      = (const float*)d_in[0];
    const float* gamma  = (const float*)d_in[1];
    const float* beta   = (const float*)d_in[2];
    const float* w_qkv  = (const float*)d_in[3];
    const float* b_qkv  = (const float*)d_in[4];
    const float* w_proj = (const float*)d_in[5];
    const float* b_proj = (const float*)d_in[6];
    float* out = (float*)d_out;

    const size_t CN = (size_t)CDIM * NSPAT;   // 524288
    const size_t NN = (size_t)NSPAT * NSPAT;  // 1048576
    const float SCALE = 0.044194173824159216f;

    // Tier selection from actual ws_size (constant across calls -> graph-safe):
    //   A: everything batched            : 4K + 16*(3CN + 2NN + CN)*4  ~ 268.4 MB
    //   B: qkv batched, attention looped : 4K + 16*3CN*4 + (2NN+CN)*4  ~ 111.2 MB
    //   C: everything per-batch          : 4K + (3CN + 2NN + CN)*4     ~  16.8 MB
    size_t needA = 4096 + (size_t)BATCH * (3 * CN + 2 * NN + CN) * 4;
    size_t needB = 4096 + (size_t)BATCH * 3 * CN * 4 + (2 * NN + CN) * 4;
    int tier = (ws_size >= needA) ? 0 : (ws_size >= needB) ? 1 : 2;

    char* ws = (char*)d_ws;
    float* stats = (float*)ws;
    float* qkv = (float*)(ws + 4096);
    size_t nqkv = (tier <= 1) ? BATCH * 3 * CN : 3 * CN;
    float* S = qkv + nqkv;
    size_t nS = (tier == 0) ? BATCH * NN : NN;
    float* P = S + nS;
    float* O = P + nS;
    float* h = out;  // GroupNorm output lives in d_out; dead before proj writes it.

    gn_stats_kernel<<<BATCH * NGROUP, 256, 0, stream>>>(x, stats);
    gn_apply_kernel<<<8192, 256, 0, stream>>>(x, gamma, beta, stats, h);

    if (tier <= 1) {
        // qkv[b][o][n] = W_qkv[o][:] . h[b][:][n] + b_qkv[o], all batches (h stride CN!)
        gemm_mfma<0, 0, 0><<<dim3(16, 24, BATCH), 256, 0, stream>>>(
            w_qkv, h, qkv, b_qkv, nullptr, 3 * CDIM, NSPAT, CDIM, CDIM, NSPAT,
            0ul, CN, 3 * CN, 0ul, 0.f);
    }

    if (tier == 0) {
        gemm_mfma<1, 0, 1><<<dim3(16, 16, BATCH), 256, 0, stream>>>(
            qkv, qkv + CN, S, nullptr, nullptr, NSPAT, NSPAT, CDIM, NSPAT, NSPAT,
            3 * CN, 3 * CN, NN, 0ul, SCALE);
        softmax_kernel<<<BATCH * NSPAT, 256, 0, stream>>>(S, P);
        gemm_mfma<0, 1, 2><<<dim3(16, 8, BATCH), 256, 0, stream>>>(
            qkv + 2 * CN, P, O, nullptr, nullptr, CDIM, NSPAT, NSPAT, NSPAT, NSPAT,
            3 * CN, NN, CN, 0ul, 0.f);
        gemm_mfma<0, 0, 3><<<dim3(16, 8, BATCH), 256, 0, stream>>>(
            w_proj, O, out, b_proj, x, CDIM, NSPAT, CDIM, CDIM, NSPAT,
            0ul, CN, CN, CN, 0.f);
    } else {
        for (int b = 0; b < BATCH; ++b) {
            const float* q;
            if (tier == 1) {
                q = qkv + (size_t)b * 3 * CN;
            } else {
                gemm_mfma<0, 0, 0><<<dim3(16, 24, 1), 256, 0, stream>>>(
                    w_qkv, h + (size_t)b * CN, qkv, b_qkv, nullptr,
                    3 * CDIM, NSPAT, CDIM, CDIM, NSPAT, 0ul, 0ul, 0ul, 0ul, 0.f);
                q = qkv;
            }
            const float* k = q + CN;
            const float* v = q + 2 * CN;
            gemm_mfma<1, 0, 1><<<dim3(16, 16, 1), 256, 0, stream>>>(
                q, k, S, nullptr, nullptr, NSPAT, NSPAT, CDIM, NSPAT, NSPAT,
                0ul, 0ul, 0ul, 0ul, SCALE);
            softmax_kernel<<<NSPAT, 256, 0, stream>>>(S, P);
            gemm_mfma<0, 1, 2><<<dim3(16, 8, 1), 256, 0, stream>>>(
                v, P, O, nullptr, nullptr, CDIM, NSPAT, NSPAT, NSPAT, NSPAT,
                0ul, 0ul, 0ul, 0ul, 0.f);
            gemm_mfma<0, 0, 3><<<dim3(16, 8, 1), 256, 0, stream>>>(
                w_proj, O, out + (size_t)b * CN, b_proj, x + (size_t)b * CN,
                CDIM, NSPAT, CDIM, CDIM, NSPAT, 0ul, 0ul, 0ul, 0ul, 0.f);
        }
    }
}

// Round 4
// 297.253 us; speedup vs baseline: 4.8303x; 4.8303x over previous
//
#include <hip/hip_runtime.h>
#include <hip/hip_bf16.h>

typedef unsigned short u16;
typedef __attribute__((ext_vector_type(8))) short short8;
typedef __attribute__((ext_vector_type(4))) float floatx4;

#define BATCH 16
#define CDIM 512
#define NSPAT 1024
#define NGROUP 8

__device__ __forceinline__ u16 f2bf(float f) {
    unsigned u = __float_as_uint(f);
    u += 0x7FFFu + ((u >> 16) & 1u);   // RNE
    return (u16)(u >> 16);
}

__device__ __forceinline__ void load_lds16(const void* g, void* l) {
    __builtin_amdgcn_global_load_lds(
        (const __attribute__((address_space(1))) unsigned int*)g,
        (__attribute__((address_space(3))) unsigned int*)l, 16, 0, 0);
}

// ---------------- fp32 -> bf16 convert (weights) ----------------
__global__ void cvt_bf16_kernel(const float* __restrict__ src, u16* __restrict__ dst, int n4) {
    int i = blockIdx.x * 256 + threadIdx.x;
    if (i < n4) {
        float4 v = ((const float4*)src)[i];
        ushort4 o;
        o.x = f2bf(v.x); o.y = f2bf(v.y); o.z = f2bf(v.z); o.w = f2bf(v.w);
        ((ushort4*)dst)[i] = o;
    }
}

// ---------------- GroupNorm stats ----------------
__global__ void gn_stats_kernel(const float* __restrict__ x, float* __restrict__ stats) {
    __shared__ float rs[4], rss[4];
    int bg = blockIdx.x;  // b*8+g; one group = 64 ch * 1024 = 65536 contiguous floats
    const float4* xv = (const float4*)(x + (size_t)bg * 65536);
    float s = 0.f, ss = 0.f;
    for (int i = threadIdx.x; i < 16384; i += 256) {
        float4 v = xv[i];
        s += v.x + v.y + v.z + v.w;
        ss += v.x * v.x + v.y * v.y + v.z * v.z + v.w * v.w;
    }
#pragma unroll
    for (int off = 32; off; off >>= 1) { s += __shfl_down(s, off); ss += __shfl_down(ss, off); }
    int wave = threadIdx.x >> 6, lane = threadIdx.x & 63;
    if (lane == 0) { rs[wave] = s; rss[wave] = ss; }
    __syncthreads();
    if (threadIdx.x == 0) {
        float S1 = rs[0] + rs[1] + rs[2] + rs[3];
        float S2 = rss[0] + rss[1] + rss[2] + rss[3];
        float mean = S1 * (1.f / 65536.f);
        float var = S2 * (1.f / 65536.f) - mean * mean;
        stats[bg * 2] = mean;
        stats[bg * 2 + 1] = rsqrtf(var + 1e-5f);
    }
}

// ---------------- GroupNorm apply + transpose: x[b][c][n] fp32 -> hT[b][n][c] bf16 ----------------
#define TSTR 66
__global__ __launch_bounds__(256) void gn_transpose_kernel(
    const float* __restrict__ x, const float* __restrict__ gamma, const float* __restrict__ beta,
    const float* __restrict__ stats, u16* __restrict__ hT) {
    __shared__ u16 t[64 * TSTR];
    int b = blockIdx.z, c0 = blockIdx.y << 6, n0 = blockIdx.x << 6;
    int tid = threadIdx.x;
    const float* xb = x + ((size_t)b * CDIM + c0) * NSPAT + n0;
#pragma unroll
    for (int p = 0; p < 4; ++p) {
        int cl = p * 16 + (tid >> 4);
        int nl = (tid & 15) << 2;
        int c = c0 + cl;
        int bg = b * NGROUP + (c >> 6);
        float ga = gamma[c] * stats[bg * 2 + 1];
        float be = beta[c] - stats[bg * 2] * ga;
        float4 v = *(const float4*)(xb + (size_t)cl * NSPAT + nl);
        u16* dst = &t[cl * TSTR + nl];
        dst[0] = f2bf(v.x * ga + be);
        dst[1] = f2bf(v.y * ga + be);
        dst[2] = f2bf(v.z * ga + be);
        dst[3] = f2bf(v.w * ga + be);
    }
    __syncthreads();
    u16* hb = hT + ((size_t)b * NSPAT + n0) * CDIM + c0;
#pragma unroll
    for (int p = 0; p < 4; ++p) {
        int nl = p * 16 + (tid >> 4);
        int cl4 = (tid & 15) << 2;
        ushort4 o;
        o.x = t[(cl4 + 0) * TSTR + nl];
        o.y = t[(cl4 + 1) * TSTR + nl];
        o.z = t[(cl4 + 2) * TSTR + nl];
        o.w = t[(cl4 + 3) * TSTR + nl];
        *(ushort4*)(hb + (size_t)nl * CDIM + cl4) = o;
    }
}

// ---------------- Softmax: S fp32 row -> P bf16 row ----------------
__global__ void softmax_kernel(const float* __restrict__ S, u16* __restrict__ P) {
    __shared__ float red[8];
    size_t row = blockIdx.x;
    const float4* sr = (const float4*)(S + (row << 10));
    float4 v = sr[threadIdx.x];
    float mx = fmaxf(fmaxf(v.x, v.y), fmaxf(v.z, v.w));
#pragma unroll
    for (int off = 32; off; off >>= 1) mx = fmaxf(mx, __shfl_down(mx, off));
    int wave = threadIdx.x >> 6, lane = threadIdx.x & 63;
    if (lane == 0) red[wave] = mx;
    __syncthreads();
    mx = fmaxf(fmaxf(red[0], red[1]), fmaxf(red[2], red[3]));
    float e0 = __expf(v.x - mx), e1 = __expf(v.y - mx), e2 = __expf(v.z - mx), e3 = __expf(v.w - mx);
    float s = e0 + e1 + e2 + e3;
#pragma unroll
    for (int off = 32; off; off >>= 1) s += __shfl_down(s, off);
    if (lane == 0) red[4 + wave] = s;
    __syncthreads();
    float inv = 1.f / (red[4] + red[5] + red[6] + red[7]);
    ushort4 o;
    o.x = f2bf(e0 * inv); o.y = f2bf(e1 * inv); o.z = f2bf(e2 * inv); o.w = f2bf(e3 * inv);
    ((ushort4*)P)[(row << 8) + threadIdx.x] = o;
}

// ---------------- 128x128x32 bf16 MFMA GEMM, global_load_lds staging ----------------
// A: bf16 [M][lda] (k-contiguous rows), B: bf16 [N][ldb] (k-contiguous rows).
// EPI 0: qkv  — +bias[R]; blockIdx.y<8 -> transposed bf16 to out0[col][R] (ldc),
//               else natural bf16 to out1[R-1024][col]
// EPI 1: S    — *scale, fp32 natural to out0 (ldc)
// EPI 2: PV   — transposed bf16 to out0[col][R] (ldc)
// EPI 3: proj — +bias[R]+resid, fp32 natural to out0 (ldc)
template <int EPI>
__global__ __launch_bounds__(256) void gemm128(
    const u16* __restrict__ A, const u16* __restrict__ B, int K, int lda, int ldb,
    unsigned long sA, unsigned long sB,
    void* __restrict__ out0, unsigned long s0, int ldc,
    void* __restrict__ out1, unsigned long s1,
    const float* __restrict__ bias, const float* __restrict__ resid, unsigned long sR,
    float scale) {
    __shared__ u16 As[128 * 32];
    __shared__ u16 Bs[128 * 32];
    int tid = threadIdx.x;
    int lane = tid & 63;
    int wave = tid >> 6;
    int quad = lane >> 4;
    int lrow = lane & 15;
    int wm = (wave >> 1) << 6;
    int wn = (wave & 1) << 6;
    int m0 = blockIdx.y << 7;
    int n0 = blockIdx.x << 7;
    const u16* Ab = A + sA * blockIdx.z;
    const u16* Bb = B + sB * blockIdx.z;

    floatx4 acc[4][4];
#pragma unroll
    for (int i = 0; i < 4; ++i)
#pragma unroll
        for (int j = 0; j < 4; ++j) acc[i][j] = (floatx4){0.f, 0.f, 0.f, 0.f};

    for (int k0 = 0; k0 < K; k0 += 32) {
#pragma unroll
        for (int it = 0; it < 2; ++it) {
            int c = it * 256 + tid;                 // chunk: 16B = 8 bf16
            int r = c >> 2, kk = (c & 3) << 3;
            load_lds16(Ab + (size_t)(m0 + r) * lda + k0 + kk, &As[c << 3]);
            load_lds16(Bb + (size_t)(n0 + r) * ldb + k0 + kk, &Bs[c << 3]);
        }
        __syncthreads();
        short8 af[4], bf[4];
#pragma unroll
        for (int i = 0; i < 4; ++i)
            af[i] = *(const short8*)&As[((wm + i * 16 + lrow) << 5) + (quad << 3)];
#pragma unroll
        for (int j = 0; j < 4; ++j)
            bf[j] = *(const short8*)&Bs[((wn + j * 16 + lrow) << 5) + (quad << 3)];
#pragma unroll
        for (int i = 0; i < 4; ++i)
#pragma unroll
            for (int j = 0; j < 4; ++j)
                acc[i][j] = __builtin_amdgcn_mfma_f32_16x16x32_bf16(af[i], bf[j], acc[i][j], 0, 0, 0);
        __syncthreads();
    }

    if (EPI == 0) {
        if (blockIdx.y < 8) {  // q,k rows (<1024): transposed store
            u16* qk = (u16*)out0 + s0 * blockIdx.z;
#pragma unroll
            for (int i = 0; i < 4; ++i)
#pragma unroll
                for (int j = 0; j < 4; ++j) {
                    int R0 = m0 + wm + i * 16 + (quad << 2);
                    int Cc = n0 + wn + j * 16 + lrow;
                    ushort4 pk;
                    pk.x = f2bf(acc[i][j][0] + bias[R0 + 0]);
                    pk.y = f2bf(acc[i][j][1] + bias[R0 + 1]);
                    pk.z = f2bf(acc[i][j][2] + bias[R0 + 2]);
                    pk.w = f2bf(acc[i][j][3] + bias[R0 + 3]);
                    *(ushort4*)&qk[(size_t)Cc * ldc + R0] = pk;
                }
        } else {  // v rows: natural store
            u16* vb = (u16*)out1 + s1 * blockIdx.z;
#pragma unroll
            for (int i = 0; i < 4; ++i)
#pragma unroll
                for (int j = 0; j < 4; ++j)
#pragma unroll
                    for (int r = 0; r < 4; ++r) {
                        int R = m0 + wm + i * 16 + (quad << 2) + r;
                        int Cc = n0 + wn + j * 16 + lrow;
                        vb[(size_t)(R - 1024) * NSPAT + Cc] = f2bf(acc[i][j][r] + bias[R]);
                    }
        }
    } else if (EPI == 1) {
        float* Sp = (float*)out0 + s0 * blockIdx.z;
#pragma unroll
        for (int i = 0; i < 4; ++i)
#pragma unroll
            for (int j = 0; j < 4; ++j)
#pragma unroll
                for (int r = 0; r < 4; ++r) {
                    int R = m0 + wm + i * 16 + (quad << 2) + r;
                    int Cc = n0 + wn + j * 16 + lrow;
                    Sp[(size_t)R * ldc + Cc] = acc[i][j][r] * scale;
                }
    } else if (EPI == 2) {
        u16* OT = (u16*)out0 + s0 * blockIdx.z;
#pragma unroll
        for (int i = 0; i < 4; ++i)
#pragma unroll
            for (int j = 0; j < 4; ++j) {
                int R0 = m0 + wm + i * 16 + (quad << 2);
                int Cc = n0 + wn + j * 16 + lrow;
                ushort4 pk;
                pk.x = f2bf(acc[i][j][0]);
                pk.y = f2bf(acc[i][j][1]);
                pk.z = f2bf(acc[i][j][2]);
                pk.w = f2bf(acc[i][j][3]);
                *(ushort4*)&OT[(size_t)Cc * ldc + R0] = pk;
            }
    } else {
        float* Op = (float*)out0 + s0 * blockIdx.z;
        const float* xr = resid + sR * blockIdx.z;
#pragma unroll
        for (int i = 0; i < 4; ++i)
#pragma unroll
            for (int j = 0; j < 4; ++j)
#pragma unroll
                for (int r = 0; r < 4; ++r) {
                    int R = m0 + wm + i * 16 + (quad << 2) + r;
                    int Cc = n0 + wn + j * 16 + lrow;
                    size_t off = (size_t)R * ldc + Cc;
                    Op[off] = acc[i][j][r] + bias[R] + xr[off];
                }
    }
}

// ---------------- launch ----------------
extern "C" void kernel_launch(void* const* d_in, const int* in_sizes, int n_in,
                              void* d_out, int out_size, void* d_ws, size_t ws_size,
                              hipStream_t stream) {
    const float* x      = (const float*)d_in[0];
    const float* gamma  = (const float*)d_in[1];
    const float* beta   = (const float*)d_in[2];
    const float* w_qkv  = (const float*)d_in[3];
    const float* b_qkv  = (const float*)d_in[4];
    const float* w_proj = (const float*)d_in[5];
    const float* b_proj = (const float*)d_in[6];
    float* out = (float*)d_out;

    const size_t CN = (size_t)CDIM * NSPAT;   // 524288
    const size_t NN = (size_t)NSPAT * NSPAT;  // 1048576
    const float SCALE = 0.044194173824159216f;

    // Workspace layout (~186.5 MB, all 16B-aligned; round-3 behavior proved ws >= 268 MB):
    char* ws = (char*)d_ws;
    float* stats  = (float*)ws;                                   // 4 KB
    u16* wqkv_bf  = (u16*)(ws + 4096);                            // 1536*512*2   = 1.5 MB
    u16* wproj_bf = wqkv_bf + (size_t)3 * CDIM * CDIM;            // 512*512*2    = 0.5 MB
    u16* hT       = wproj_bf + (size_t)CDIM * CDIM;               // 16*1024*512  bf16 = 16.8 MB
    u16* qkT      = hT + BATCH * CN;                              // 16*1024*1024 bf16 = 33.5 MB
    u16* v_bf     = qkT + BATCH * NN;                             // 16*512*1024  bf16 = 16.8 MB
    u16* OT       = v_bf + BATCH * CN;                            // 16*1024*512  bf16 = 16.8 MB
    u16* P        = OT + BATCH * CN;                              // 16*1024*1024 bf16 = 33.5 MB
    float* S      = (float*)(P + BATCH * NN);                     // 16*1024*1024 fp32 = 67 MB

    // weights -> bf16
    cvt_bf16_kernel<<<768, 256, 0, stream>>>(w_qkv, wqkv_bf, 3 * CDIM * CDIM / 4);
    cvt_bf16_kernel<<<256, 256, 0, stream>>>(w_proj, wproj_bf, CDIM * CDIM / 4);

    gn_stats_kernel<<<BATCH * NGROUP, 256, 0, stream>>>(x, stats);
    gn_transpose_kernel<<<dim3(NSPAT / 64, CDIM / 64, BATCH), 256, 0, stream>>>(
        x, gamma, beta, stats, hT);

    // qkv: M=1536 (o), N=1024 (n), K=512 (c). A=W_qkv bf16 [o][c], B=hT [n][c].
    // rows<1024 -> qkT[n][o] transposed (ldc=1024); rows>=1024 -> v[c][n] natural.
    gemm128<0><<<dim3(8, 12, BATCH), 256, 0, stream>>>(
        wqkv_bf, hT, CDIM, CDIM, CDIM, 0ul, CN,
        qkT, NN, NSPAT, v_bf, CN, b_qkv, nullptr, 0ul, 0.f);

    // scores: M=i, N=j, K=c=512. A=qT=qkT[:, :512], B=kT=qkT[:, 512:]; both lda/ldb=1024.
    gemm128<1><<<dim3(8, 8, BATCH), 256, 0, stream>>>(
        qkT, qkT + CDIM, CDIM, NSPAT, NSPAT, NN, NN,
        S, NN, NSPAT, nullptr, 0ul, nullptr, nullptr, 0ul, SCALE);

    softmax_kernel<<<BATCH * NSPAT, 256, 0, stream>>>(S, P);

    // PV: M=c (512), N=i (1024), K=j (1024). A=v[c][j], B=P[i][j]. Out: OT[i][c] (ldc=512).
    gemm128<2><<<dim3(8, 4, BATCH), 256, 0, stream>>>(
        v_bf, P, NSPAT, NSPAT, NSPAT, CN, NN,
        OT, CN, CDIM, nullptr, 0ul, nullptr, nullptr, 0ul, 0.f);

    // proj: M=o (512), N=n (1024), K=c=512. A=W_proj bf16, B=OT[n][c]. +bias +x residual.
    gemm128<3><<<dim3(8, 4, BATCH), 256, 0, stream>>>(
        wproj_bf, OT, CDIM, CDIM, CDIM, 0ul, CN,
        out, CN, NSPAT, nullptr, 0ul, b_proj, x, CN, 0.f);
}

// Round 6
// 282.883 us; speedup vs baseline: 5.0757x; 1.0508x over previous
//
#include <hip/hip_runtime.h>
#include <hip/hip_bf16.h>

typedef unsigned short u16;
typedef __attribute__((ext_vector_type(8))) short short8;
typedef __attribute__((ext_vector_type(4))) float floatx4;

#define BATCH 16
#define CDIM 512
#define NSPAT 1024
#define NGROUP 8

__device__ __forceinline__ float bf2f(u16 u) {
    return __uint_as_float(((unsigned)u) << 16);
}
__device__ __forceinline__ u16 f2bf(float f) {
    unsigned u = __float_as_uint(f);
    u += 0x7FFFu + ((u >> 16) & 1u);   // RNE
    return (u16)(u >> 16);
}

__device__ __forceinline__ void load_lds16(const void* g, void* l) {
    __builtin_amdgcn_global_load_lds(
        (const __attribute__((address_space(1))) unsigned int*)g,
        (__attribute__((address_space(3))) unsigned int*)l, 16, 0, 0);
}

// ---------------- fp32 -> bf16 convert (weights) ----------------
__global__ void cvt_bf16_kernel(const float* __restrict__ src, u16* __restrict__ dst, int n4) {
    int i = blockIdx.x * 256 + threadIdx.x;
    if (i < n4) {
        float4 v = ((const float4*)src)[i];
        ushort4 o;
        o.x = f2bf(v.x); o.y = f2bf(v.y); o.z = f2bf(v.z); o.w = f2bf(v.w);
        ((ushort4*)dst)[i] = o;
    }
}

// ---------------- GroupNorm stats ----------------
__global__ void gn_stats_kernel(const float* __restrict__ x, float* __restrict__ stats) {
    __shared__ float rs[4], rss[4];
    int bg = blockIdx.x;  // b*8+g; one group = 64 ch * 1024 = 65536 contiguous floats
    const float4* xv = (const float4*)(x + (size_t)bg * 65536);
    float s = 0.f, ss = 0.f;
    for (int i = threadIdx.x; i < 16384; i += 256) {
        float4 v = xv[i];
        s += v.x + v.y + v.z + v.w;
        ss += v.x * v.x + v.y * v.y + v.z * v.z + v.w * v.w;
    }
#pragma unroll
    for (int off = 32; off; off >>= 1) { s += __shfl_down(s, off); ss += __shfl_down(ss, off); }
    int wave = threadIdx.x >> 6, lane = threadIdx.x & 63;
    if (lane == 0) { rs[wave] = s; rss[wave] = ss; }
    __syncthreads();
    if (threadIdx.x == 0) {
        float S1 = rs[0] + rs[1] + rs[2] + rs[3];
        float S2 = rss[0] + rss[1] + rss[2] + rss[3];
        float mean = S1 * (1.f / 65536.f);
        float var = S2 * (1.f / 65536.f) - mean * mean;
        stats[bg * 2] = mean;
        stats[bg * 2 + 1] = rsqrtf(var + 1e-5f);
    }
}

// ---------------- GroupNorm apply + transpose: x[b][c][n] fp32 -> hT[b][n][c] bf16 ----------------
#define TSTR 66
__global__ __launch_bounds__(256) void gn_transpose_kernel(
    const float* __restrict__ x, const float* __restrict__ gamma, const float* __restrict__ beta,
    const float* __restrict__ stats, u16* __restrict__ hT) {
    __shared__ u16 t[64 * TSTR];
    int b = blockIdx.z, c0 = blockIdx.y << 6, n0 = blockIdx.x << 6;
    int tid = threadIdx.x;
    const float* xb = x + ((size_t)b * CDIM + c0) * NSPAT + n0;
#pragma unroll
    for (int p = 0; p < 4; ++p) {
        int cl = p * 16 + (tid >> 4);
        int nl = (tid & 15) << 2;
        int c = c0 + cl;
        int bg = b * NGROUP + (c >> 6);
        float ga = gamma[c] * stats[bg * 2 + 1];
        float be = beta[c] - stats[bg * 2] * ga;
        float4 v = *(const float4*)(xb + (size_t)cl * NSPAT + nl);
        u16* dst = &t[cl * TSTR + nl];
        dst[0] = f2bf(v.x * ga + be);
        dst[1] = f2bf(v.y * ga + be);
        dst[2] = f2bf(v.z * ga + be);
        dst[3] = f2bf(v.w * ga + be);
    }
    __syncthreads();
    u16* hb = hT + ((size_t)b * NSPAT + n0) * CDIM + c0;
#pragma unroll
    for (int p = 0; p < 4; ++p) {
        int nl = p * 16 + (tid >> 4);
        int cl4 = (tid & 15) << 2;
        ushort4 o;
        o.x = t[(cl4 + 0) * TSTR + nl];
        o.y = t[(cl4 + 1) * TSTR + nl];
        o.z = t[(cl4 + 2) * TSTR + nl];
        o.w = t[(cl4 + 3) * TSTR + nl];
        *(ushort4*)(hb + (size_t)nl * CDIM + cl4) = o;
    }
}

// ---------------- Row sums of unnormalized P: linv[b][i] = 1 / sum_j P[b][i][j] ----------------
// One wave per row of 1024 bf16: 2 passes x 64 lanes x 8 elems = 1024.
__global__ void rowsum_kernel(const u16* __restrict__ P, float* __restrict__ linv) {
    int row = blockIdx.x * 4 + (threadIdx.x >> 6);  // 4 waves per block, 1 row each
    int lane = threadIdx.x & 63;
    const short8* pr = (const short8*)(P + ((size_t)row << 10));
    float s = 0.f;
#pragma unroll
    for (int t = 0; t < 2; ++t) {
        short8 v = pr[t * 64 + lane];
#pragma unroll
        for (int j = 0; j < 8; ++j) s += bf2f((u16)v[j]);
    }
#pragma unroll
    for (int off = 32; off; off >>= 1) s += __shfl_down(s, off);
    if (lane == 0) linv[row] = 1.f / s;
}

// ---------------- 128x128x32 bf16 MFMA GEMM, global_load_lds staging ----------------
// A: bf16 [M][lda] (k-contiguous rows), B: bf16 [N][ldb] (k-contiguous rows).
// EPI 0: qkv  — +bias[R]; blockIdx.y<8 -> transposed bf16 to out0[col][R] (ldc),
//               else natural bf16 to out1[R-1024][col]
// EPI 1: scores -> P: exp(acc*scale), bf16 natural to out0 (ldc)   [maxless softmax numerator]
// EPI 2: PV   — *resid[col] (rowscale linv), transposed bf16 to out0[col][R] (ldc)
// EPI 3: proj — +bias[R]+resid, fp32 natural to out0 (ldc)
template <int EPI>
__global__ __launch_bounds__(256) void gemm128(
    const u16* __restrict__ A, const u16* __restrict__ B, int K, int lda, int ldb,
    unsigned long sA, unsigned long sB,
    void* __restrict__ out0, unsigned long s0, int ldc,
    void* __restrict__ out1, unsigned long s1,
    const float* __restrict__ bias, const float* __restrict__ resid, unsigned long sR,
    float scale) {
    __shared__ u16 As[128 * 32];
    __shared__ u16 Bs[128 * 32];
    int tid = threadIdx.x;
    int lane = tid & 63;
    int wave = tid >> 6;
    int quad = lane >> 4;
    int lrow = lane & 15;
    int wm = (wave >> 1) << 6;
    int wn = (wave & 1) << 6;
    int m0 = blockIdx.y << 7;
    int n0 = blockIdx.x << 7;
    const u16* Ab = A + sA * blockIdx.z;
    const u16* Bb = B + sB * blockIdx.z;

    floatx4 acc[4][4];
#pragma unroll
    for (int i = 0; i < 4; ++i)
#pragma unroll
        for (int j = 0; j < 4; ++j) acc[i][j] = (floatx4){0.f, 0.f, 0.f, 0.f};

    for (int k0 = 0; k0 < K; k0 += 32) {
#pragma unroll
        for (int it = 0; it < 2; ++it) {
            int c = it * 256 + tid;                 // chunk: 16B = 8 bf16
            int r = c >> 2, kk = (c & 3) << 3;
            load_lds16(Ab + (size_t)(m0 + r) * lda + k0 + kk, &As[c << 3]);
            load_lds16(Bb + (size_t)(n0 + r) * ldb + k0 + kk, &Bs[c << 3]);
        }
        __syncthreads();
        short8 af[4], bf[4];
#pragma unroll
        for (int i = 0; i < 4; ++i)
            af[i] = *(const short8*)&As[((wm + i * 16 + lrow) << 5) + (quad << 3)];
#pragma unroll
        for (int j = 0; j < 4; ++j)
            bf[j] = *(const short8*)&Bs[((wn + j * 16 + lrow) << 5) + (quad << 3)];
#pragma unroll
        for (int i = 0; i < 4; ++i)
#pragma unroll
            for (int j = 0; j < 4; ++j)
                acc[i][j] = __builtin_amdgcn_mfma_f32_16x16x32_bf16(af[i], bf[j], acc[i][j], 0, 0, 0);
        __syncthreads();
    }

    if (EPI == 0) {
        if (blockIdx.y < 8) {  // q,k rows (<1024): transposed store
            u16* qk = (u16*)out0 + s0 * blockIdx.z;
#pragma unroll
            for (int i = 0; i < 4; ++i)
#pragma unroll
                for (int j = 0; j < 4; ++j) {
                    int R0 = m0 + wm + i * 16 + (quad << 2);
                    int Cc = n0 + wn + j * 16 + lrow;
                    ushort4 pk;
                    pk.x = f2bf(acc[i][j][0] + bias[R0 + 0]);
                    pk.y = f2bf(acc[i][j][1] + bias[R0 + 1]);
                    pk.z = f2bf(acc[i][j][2] + bias[R0 + 2]);
                    pk.w = f2bf(acc[i][j][3] + bias[R0 + 3]);
                    *(ushort4*)&qk[(size_t)Cc * ldc + R0] = pk;
                }
        } else {  // v rows: natural store
            u16* vb = (u16*)out1 + s1 * blockIdx.z;
#pragma unroll
            for (int i = 0; i < 4; ++i)
#pragma unroll
                for (int j = 0; j < 4; ++j)
#pragma unroll
                    for (int r = 0; r < 4; ++r) {
                        int R = m0 + wm + i * 16 + (quad << 2) + r;
                        int Cc = n0 + wn + j * 16 + lrow;
                        vb[(size_t)(R - 1024) * NSPAT + Cc] = f2bf(acc[i][j][r] + bias[R]);
                    }
        }
    } else if (EPI == 1) {
        u16* Pp = (u16*)out0 + s0 * blockIdx.z;
#pragma unroll
        for (int i = 0; i < 4; ++i)
#pragma unroll
            for (int j = 0; j < 4; ++j)
#pragma unroll
                for (int r = 0; r < 4; ++r) {
                    int R = m0 + wm + i * 16 + (quad << 2) + r;
                    int Cc = n0 + wn + j * 16 + lrow;
                    Pp[(size_t)R * ldc + Cc] = f2bf(__expf(acc[i][j][r] * scale));
                }
    } else if (EPI == 2) {
        u16* OT = (u16*)out0 + s0 * blockIdx.z;
        const float* li = resid + sR * blockIdx.z;
#pragma unroll
        for (int i = 0; i < 4; ++i)
#pragma unroll
            for (int j = 0; j < 4; ++j) {
                int R0 = m0 + wm + i * 16 + (quad << 2);
                int Cc = n0 + wn + j * 16 + lrow;
                float sc = li[Cc];
                ushort4 pk;
                pk.x = f2bf(acc[i][j][0] * sc);
                pk.y = f2bf(acc[i][j][1] * sc);
                pk.z = f2bf(acc[i][j][2] * sc);
                pk.w = f2bf(acc[i][j][3] * sc);
                *(ushort4*)&OT[(size_t)Cc * ldc + R0] = pk;
            }
    } else {
        float* Op = (float*)out0 + s0 * blockIdx.z;
        const float* xr = resid + sR * blockIdx.z;
#pragma unroll
        for (int i = 0; i < 4; ++i)
#pragma unroll
            for (int j = 0; j < 4; ++j)
#pragma unroll
                for (int r = 0; r < 4; ++r) {
                    int R = m0 + wm + i * 16 + (quad << 2) + r;
                    int Cc = n0 + wn + j * 16 + lrow;
                    size_t off = (size_t)R * ldc + Cc;
                    Op[off] = acc[i][j][r] + bias[R] + xr[off];
                }
    }
}

// ---------------- launch ----------------
extern "C" void kernel_launch(void* const* d_in, const int* in_sizes, int n_in,
                              void* d_out, int out_size, void* d_ws, size_t ws_size,
                              hipStream_t stream) {
    const float* x      = (const float*)d_in[0];
    const float* gamma  = (const float*)d_in[1];
    const float* beta   = (const float*)d_in[2];
    const float* w_qkv  = (const float*)d_in[3];
    const float* b_qkv  = (const float*)d_in[4];
    const float* w_proj = (const float*)d_in[5];
    const float* b_proj = (const float*)d_in[6];
    float* out = (float*)d_out;

    const size_t CN = (size_t)CDIM * NSPAT;   // 524288
    const size_t NN = (size_t)NSPAT * NSPAT;  // 1048576
    const float SCALE = 0.044194173824159216f;

    // Workspace layout (~120 MB; round 4 proved ws >= 186.5 MB):
    char* ws = (char*)d_ws;
    float* stats  = (float*)ws;                                   // 4 KB
    u16* wqkv_bf  = (u16*)(ws + 4096);                            // 1.5 MB
    u16* wproj_bf = wqkv_bf + (size_t)3 * CDIM * CDIM;            // 0.5 MB
    u16* hT       = wproj_bf + (size_t)CDIM * CDIM;               // 16.8 MB  [n][c] bf16
    u16* qkT      = hT + BATCH * CN;                              // 33.5 MB  [n][o<1024] bf16
    u16* v_bf     = qkT + BATCH * NN;                             // 16.8 MB  [c][n] bf16
    u16* OT       = v_bf + BATCH * CN;                            // 16.8 MB  [i][c] bf16
    u16* P        = OT + BATCH * CN;                              // 33.5 MB  [i][j] bf16 (unnormalized)
    float* linv   = (float*)(P + BATCH * NN);                     // 64 KB

    // weights -> bf16
    cvt_bf16_kernel<<<768, 256, 0, stream>>>(w_qkv, wqkv_bf, 3 * CDIM * CDIM / 4);
    cvt_bf16_kernel<<<256, 256, 0, stream>>>(w_proj, wproj_bf, CDIM * CDIM / 4);

    gn_stats_kernel<<<BATCH * NGROUP, 256, 0, stream>>>(x, stats);
    gn_transpose_kernel<<<dim3(NSPAT / 64, CDIM / 64, BATCH), 256, 0, stream>>>(
        x, gamma, beta, stats, hT);

    // qkv: M=1536 (o), N=1024 (n), K=512 (c). A=W_qkv bf16 [o][c], B=hT [n][c].
    gemm128<0><<<dim3(8, 12, BATCH), 256, 0, stream>>>(
        wqkv_bf, hT, CDIM, CDIM, CDIM, 0ul, CN,
        qkT, NN, NSPAT, v_bf, CN, b_qkv, nullptr, 0ul, 0.f);

    // scores->P: M=i, N=j, K=c=512. A=qT, B=kT. Epilogue: P = exp(scale*acc) bf16.
    gemm128<1><<<dim3(8, 8, BATCH), 256, 0, stream>>>(
        qkT, qkT + CDIM, CDIM, NSPAT, NSPAT, NN, NN,
        P, NN, NSPAT, nullptr, 0ul, nullptr, nullptr, 0ul, SCALE);

    rowsum_kernel<<<BATCH * NSPAT / 4, 256, 0, stream>>>(P, linv);

    // PV: M=c (512), N=i (1024), K=j (1024). A=v[c][j], B=P[i][j].
    // Epilogue: *linv[i], out OT[i][c] (ldc=512).
    gemm128<2><<<dim3(8, 4, BATCH), 256, 0, stream>>>(
        v_bf, P, NSPAT, NSPAT, NSPAT, CN, NN,
        OT, CN, CDIM, nullptr, 0ul, nullptr, linv, NSPAT, 0.f);

    // proj: M=o (512), N=n (1024), K=c=512. A=W_proj bf16, B=OT[n][c]. +bias +x residual.
    gemm128<3><<<dim3(8, 4, BATCH), 256, 0, stream>>>(
        wproj_bf, OT, CDIM, CDIM, CDIM, 0ul, CN,
        out, CN, NSPAT, nullptr, 0ul, b_proj, x, CN, 0.f);
}

// Round 7
// 256.078 us; speedup vs baseline: 5.6070x; 1.1047x over previous
//
#include <hip/hip_runtime.h>
#include <hip/hip_bf16.h>

typedef unsigned short u16;
typedef __attribute__((ext_vector_type(8))) short short8;
typedef __attribute__((ext_vector_type(4))) float floatx4;

#define BATCH 16
#define CDIM 512
#define NSPAT 1024
#define NGROUP 8

__device__ __forceinline__ u16 f2bf(float f) {
    unsigned u = __float_as_uint(f);
    u += 0x7FFFu + ((u >> 16) & 1u);   // RNE
    return (u16)(u >> 16);
}

__device__ __forceinline__ void load_lds16(const void* g, void* l) {
    __builtin_amdgcn_global_load_lds(
        (const __attribute__((address_space(1))) unsigned int*)g,
        (__attribute__((address_space(3))) unsigned int*)l, 16, 0, 0);
}

// ---------------- prep: weights->bf16 + GroupNorm stats (one launch) ----------------
// blocks [0,768): w_qkv cvt; [768,1024): w_proj cvt; [1024,1152): gn stats
__global__ __launch_bounds__(256) void prep_kernel(
    const float* __restrict__ w_qkv, const float* __restrict__ w_proj,
    u16* __restrict__ wqkv_bf, u16* __restrict__ wproj_bf,
    const float* __restrict__ x, float* __restrict__ stats) {
    int b = blockIdx.x;
    if (b < 1024) {
        const float* src = (b < 768) ? w_qkv : w_proj;
        u16* dst = (b < 768) ? wqkv_bf : wproj_bf;
        int i = (b < 768 ? b : b - 768) * 256 + threadIdx.x;
        float4 v = ((const float4*)src)[i];
        ushort4 o;
        o.x = f2bf(v.x); o.y = f2bf(v.y); o.z = f2bf(v.z); o.w = f2bf(v.w);
        ((ushort4*)dst)[i] = o;
        return;
    }
    __shared__ float rs[4], rss[4];
    int bg = b - 1024;  // 0..127; one group = 65536 contiguous floats
    const float4* xv = (const float4*)(x + (size_t)bg * 65536);
    float s = 0.f, ss = 0.f;
    for (int i = threadIdx.x; i < 16384; i += 256) {
        float4 v = xv[i];
        s += v.x + v.y + v.z + v.w;
        ss += v.x * v.x + v.y * v.y + v.z * v.z + v.w * v.w;
    }
#pragma unroll
    for (int off = 32; off; off >>= 1) { s += __shfl_down(s, off); ss += __shfl_down(ss, off); }
    int wave = threadIdx.x >> 6, lane = threadIdx.x & 63;
    if (lane == 0) { rs[wave] = s; rss[wave] = ss; }
    __syncthreads();
    if (threadIdx.x == 0) {
        float S1 = rs[0] + rs[1] + rs[2] + rs[3];
        float S2 = rss[0] + rss[1] + rss[2] + rss[3];
        float mean = S1 * (1.f / 65536.f);
        float var = S2 * (1.f / 65536.f) - mean * mean;
        stats[bg * 2] = mean;
        stats[bg * 2 + 1] = rsqrtf(var + 1e-5f);
    }
}

// ---------------- GroupNorm apply + transpose: x[b][c][n] fp32 -> hT[b][n][c] bf16 ----------------
#define TSTR 66
__global__ __launch_bounds__(256) void gn_transpose_kernel(
    const float* __restrict__ x, const float* __restrict__ gamma, const float* __restrict__ beta,
    const float* __restrict__ stats, u16* __restrict__ hT) {
    __shared__ u16 t[64 * TSTR];
    int b = blockIdx.z, c0 = blockIdx.y << 6, n0 = blockIdx.x << 6;
    int tid = threadIdx.x;
    const float* xb = x + ((size_t)b * CDIM + c0) * NSPAT + n0;
#pragma unroll
    for (int p = 0; p < 4; ++p) {
        int cl = p * 16 + (tid >> 4);
        int nl = (tid & 15) << 2;
        int c = c0 + cl;
        int bg = b * NGROUP + (c >> 6);
        float ga = gamma[c] * stats[bg * 2 + 1];
        float be = beta[c] - stats[bg * 2] * ga;
        float4 v = *(const float4*)(xb + (size_t)cl * NSPAT + nl);
        u16* dst = &t[cl * TSTR + nl];
        dst[0] = f2bf(v.x * ga + be);
        dst[1] = f2bf(v.y * ga + be);
        dst[2] = f2bf(v.z * ga + be);
        dst[3] = f2bf(v.w * ga + be);
    }
    __syncthreads();
    u16* hb = hT + ((size_t)b * NSPAT + n0) * CDIM + c0;
#pragma unroll
    for (int p = 0; p < 4; ++p) {
        int nl = p * 16 + (tid >> 4);
        int cl4 = (tid & 15) << 2;
        ushort4 o;
        o.x = t[(cl4 + 0) * TSTR + nl];
        o.y = t[(cl4 + 1) * TSTR + nl];
        o.z = t[(cl4 + 2) * TSTR + nl];
        o.w = t[(cl4 + 3) * TSTR + nl];
        *(ushort4*)(hb + (size_t)nl * CDIM + cl4) = o;
    }
}

// ---------------- 128x128x64 bf16 MFMA GEMM, global_load_lds + XOR-swizzled LDS ----------------
// LDS tile: 128 rows x 64 shorts (8 chunks of 16B). Slot (r,p) holds global k-chunk p^(r&7);
// reader of (R, chunk q) uses p = q^(R&7). Within a 16-lane read phase rows hit each 4-bank
// group exactly twice -> conflict-free (2-way is free).
// A: bf16 [M][lda] k-contig rows, B: bf16 [N][ldb] k-contig rows.
// EPI 0: qkv  — +bias[R]; blockIdx.y<8 -> transposed bf16 out0[col][R] (ldc), else natural out1
// EPI 1: scores -> P = exp(acc*scale) bf16 natural; fused row sums atomicAdd into lsums
// EPI 2: PV   — *rcp(lsums[col]), transposed bf16 out0[col][R] (ldc)
// EPI 3: proj — +bias[R]+resid, fp32 natural out0 (ldc)
template <int EPI>
__global__ __launch_bounds__(256) void gemm128(
    const u16* __restrict__ A, const u16* __restrict__ B, int K, int lda, int ldb,
    unsigned long sA, unsigned long sB,
    void* __restrict__ out0, unsigned long s0, int ldc,
    void* __restrict__ out1, unsigned long s1,
    const float* __restrict__ bias, float* __restrict__ lsums,
    const float* __restrict__ resid, unsigned long sR, float scale) {
    __shared__ u16 As[128 * 64];
    __shared__ u16 Bs[128 * 64];
    int tid = threadIdx.x;
    int lane = tid & 63;
    int wave = tid >> 6;
    int quad = lane >> 4;
    int lrow = lane & 15;
    int wm = (wave >> 1) << 6;
    int wn = (wave & 1) << 6;
    int m0 = blockIdx.y << 7;
    int n0 = blockIdx.x << 7;
    const u16* Ab = A + sA * blockIdx.z;
    const u16* Bb = B + sB * blockIdx.z;

    floatx4 acc[4][4];
#pragma unroll
    for (int i = 0; i < 4; ++i)
#pragma unroll
        for (int j = 0; j < 4; ++j) acc[i][j] = (floatx4){0.f, 0.f, 0.f, 0.f};

    for (int k0 = 0; k0 < K; k0 += 64) {
#pragma unroll
        for (int it = 0; it < 4; ++it) {
            int c = it * 256 + tid;             // 1024 chunks of 16B per tile
            int r = c >> 3, p = c & 7;
            int kc = p ^ (r & 7);               // global chunk fetched into slot p
            load_lds16(Ab + (size_t)(m0 + r) * lda + k0 + (kc << 3), &As[c << 3]);
            load_lds16(Bb + (size_t)(n0 + r) * ldb + k0 + (kc << 3), &Bs[c << 3]);
        }
        __syncthreads();
#pragma unroll
        for (int s = 0; s < 2; ++s) {
            short8 af[4], bf[4];
#pragma unroll
            for (int i = 0; i < 4; ++i) {
                int R = wm + i * 16 + lrow;
                int p = (s * 4 + quad) ^ (R & 7);
                af[i] = *(const short8*)&As[(R << 6) + (p << 3)];
            }
#pragma unroll
            for (int j = 0; j < 4; ++j) {
                int R = wn + j * 16 + lrow;
                int p = (s * 4 + quad) ^ (R & 7);
                bf[j] = *(const short8*)&Bs[(R << 6) + (p << 3)];
            }
#pragma unroll
            for (int i = 0; i < 4; ++i)
#pragma unroll
                for (int j = 0; j < 4; ++j)
                    acc[i][j] = __builtin_amdgcn_mfma_f32_16x16x32_bf16(af[i], bf[j], acc[i][j], 0, 0, 0);
        }
        __syncthreads();
    }

    if (EPI == 0) {
        if (blockIdx.y < 8) {  // q,k rows (<1024): transposed store
            u16* qk = (u16*)out0 + s0 * blockIdx.z;
#pragma unroll
            for (int i = 0; i < 4; ++i)
#pragma unroll
                for (int j = 0; j < 4; ++j) {
                    int R0 = m0 + wm + i * 16 + (quad << 2);
                    int Cc = n0 + wn + j * 16 + lrow;
                    ushort4 pk;
                    pk.x = f2bf(acc[i][j][0] + bias[R0 + 0]);
                    pk.y = f2bf(acc[i][j][1] + bias[R0 + 1]);
                    pk.z = f2bf(acc[i][j][2] + bias[R0 + 2]);
                    pk.w = f2bf(acc[i][j][3] + bias[R0 + 3]);
                    *(ushort4*)&qk[(size_t)Cc * ldc + R0] = pk;
                }
        } else {  // v rows: natural store
            u16* vb = (u16*)out1 + s1 * blockIdx.z;
#pragma unroll
            for (int i = 0; i < 4; ++i)
#pragma unroll
                for (int j = 0; j < 4; ++j)
#pragma unroll
                    for (int r = 0; r < 4; ++r) {
                        int R = m0 + wm + i * 16 + (quad << 2) + r;
                        int Cc = n0 + wn + j * 16 + lrow;
                        vb[(size_t)(R - 1024) * NSPAT + Cc] = f2bf(acc[i][j][r] + bias[R]);
                    }
        }
    } else if (EPI == 1) {
        u16* Pp = (u16*)out0 + s0 * blockIdx.z;
        float rowpart[4][4];
#pragma unroll
        for (int i = 0; i < 4; ++i)
#pragma unroll
            for (int r = 0; r < 4; ++r) rowpart[i][r] = 0.f;
#pragma unroll
        for (int i = 0; i < 4; ++i)
#pragma unroll
            for (int j = 0; j < 4; ++j)
#pragma unroll
                for (int r = 0; r < 4; ++r) {
                    int R = m0 + wm + i * 16 + (quad << 2) + r;
                    int Cc = n0 + wn + j * 16 + lrow;
                    float e = __expf(acc[i][j][r] * scale);
                    rowpart[i][r] += e;
                    Pp[(size_t)R * ldc + Cc] = f2bf(e);
                }
        // reduce across the 16 lanes of each quad (they share rows, differ in cols)
#pragma unroll
        for (int i = 0; i < 4; ++i)
#pragma unroll
            for (int r = 0; r < 4; ++r) {
                float v = rowpart[i][r];
#pragma unroll
                for (int m = 1; m < 16; m <<= 1) v += __shfl_xor(v, m);
                if (lrow == 0) {
                    int R = m0 + wm + i * 16 + (quad << 2) + r;
                    atomicAdd(&lsums[(size_t)blockIdx.z * NSPAT + R], v);
                }
            }
    } else if (EPI == 2) {
        u16* OT = (u16*)out0 + s0 * blockIdx.z;
        const float* li = lsums + (size_t)blockIdx.z * NSPAT;
#pragma unroll
        for (int i = 0; i < 4; ++i)
#pragma unroll
            for (int j = 0; j < 4; ++j) {
                int R0 = m0 + wm + i * 16 + (quad << 2);
                int Cc = n0 + wn + j * 16 + lrow;
                float sc = __builtin_amdgcn_rcpf(li[Cc]);
                ushort4 pk;
                pk.x = f2bf(acc[i][j][0] * sc);
                pk.y = f2bf(acc[i][j][1] * sc);
                pk.z = f2bf(acc[i][j][2] * sc);
                pk.w = f2bf(acc[i][j][3] * sc);
                *(ushort4*)&OT[(size_t)Cc * ldc + R0] = pk;
            }
    } else {
        float* Op = (float*)out0 + s0 * blockIdx.z;
        const float* xr = resid + sR * blockIdx.z;
#pragma unroll
        for (int i = 0; i < 4; ++i)
#pragma unroll
            for (int j = 0; j < 4; ++j)
#pragma unroll
                for (int r = 0; r < 4; ++r) {
                    int R = m0 + wm + i * 16 + (quad << 2) + r;
                    int Cc = n0 + wn + j * 16 + lrow;
                    size_t off = (size_t)R * ldc + Cc;
                    Op[off] = acc[i][j][r] + bias[R] + xr[off];
                }
    }
}

// ---------------- launch ----------------
extern "C" void kernel_launch(void* const* d_in, const int* in_sizes, int n_in,
                              void* d_out, int out_size, void* d_ws, size_t ws_size,
                              hipStream_t stream) {
    const float* x      = (const float*)d_in[0];
    const float* gamma  = (const float*)d_in[1];
    const float* beta   = (const float*)d_in[2];
    const float* w_qkv  = (const float*)d_in[3];
    const float* b_qkv  = (const float*)d_in[4];
    const float* w_proj = (const float*)d_in[5];
    const float* b_proj = (const float*)d_in[6];
    float* out = (float*)d_out;

    const size_t CN = (size_t)CDIM * NSPAT;   // 524288
    const size_t NN = (size_t)NSPAT * NSPAT;  // 1048576
    const float SCALE = 0.044194173824159216f;

    // Workspace layout (~120 MB; ws >= 186.5 MB proven in round 4):
    char* ws = (char*)d_ws;
    float* stats  = (float*)ws;                                   // 4 KB
    u16* wqkv_bf  = (u16*)(ws + 4096);                            // 1.5 MB
    u16* wproj_bf = wqkv_bf + (size_t)3 * CDIM * CDIM;            // 0.5 MB
    u16* hT       = wproj_bf + (size_t)CDIM * CDIM;               // 16.8 MB  [n][c] bf16
    u16* qkT      = hT + BATCH * CN;                              // 33.5 MB  [n][o<1024] bf16
    u16* v_bf     = qkT + BATCH * NN;                             // 16.8 MB  [c][n] bf16
    u16* OT       = v_bf + BATCH * CN;                            // 16.8 MB  [i][c] bf16
    u16* P        = OT + BATCH * CN;                              // 33.5 MB  [i][j] bf16 (unnormalized)
    float* lsums  = (float*)(P + BATCH * NN);                     // 64 KB raw softmax denominators

    prep_kernel<<<1152, 256, 0, stream>>>(w_qkv, w_proj, wqkv_bf, wproj_bf, x, stats);
    hipMemsetAsync(lsums, 0, BATCH * NSPAT * sizeof(float), stream);

    gn_transpose_kernel<<<dim3(NSPAT / 64, CDIM / 64, BATCH), 256, 0, stream>>>(
        x, gamma, beta, stats, hT);

    // qkv: M=1536 (o), N=1024 (n), K=512 (c). A=W_qkv bf16 [o][c], B=hT [n][c].
    gemm128<0><<<dim3(8, 12, BATCH), 256, 0, stream>>>(
        wqkv_bf, hT, CDIM, CDIM, CDIM, 0ul, CN,
        qkT, NN, NSPAT, v_bf, CN, b_qkv, nullptr, nullptr, 0ul, 0.f);

    // scores->P: M=i, N=j, K=c=512. A=qT, B=kT. P = exp(scale*acc); fused row sums.
    gemm128<1><<<dim3(8, 8, BATCH), 256, 0, stream>>>(
        qkT, qkT + CDIM, CDIM, NSPAT, NSPAT, NN, NN,
        P, NN, NSPAT, nullptr, 0ul, nullptr, lsums, nullptr, 0ul, SCALE);

    // PV: M=c (512), N=i (1024), K=j (1024). A=v[c][j], B=P[i][j].
    // Epilogue: *rcp(lsums[i]), out OT[i][c] (ldc=512).
    gemm128<2><<<dim3(8, 4, BATCH), 256, 0, stream>>>(
        v_bf, P, NSPAT, NSPAT, NSPAT, CN, NN,
        OT, CN, CDIM, nullptr, 0ul, nullptr, lsums, nullptr, 0ul, 0.f);

    // proj: M=o (512), N=n (1024), K=c=512. A=W_proj bf16, B=OT[n][c]. +bias +x residual.
    gemm128<3><<<dim3(8, 4, BATCH), 256, 0, stream>>>(
        wproj_bf, OT, CDIM, CDIM, CDIM, 0ul, CN,
        out, CN, NSPAT, nullptr, 0ul, b_proj, nullptr, x, CN, 0.f);
}